// Round 7
// baseline (32.849 us; speedup 1.0000x reference)
//
#include <hip/hip_runtime.h>
#include <hip/hip_bf16.h>

// GATv2 dense complete-graph, B=32, W=128 (in-feat), F=64 (nodes), H=2, D=128.
// SINGLE fused kernel: block = (b, i-tile of 8), grid 256 = CU count.
// Each block recomputes el for all 64 nodes (both heads) from x + Wl (8x
// redundant, ~6.8us VALU GPU-wide) to avoid any cross-block dependency,
// then er for its 8 rows, scores + shfl softmax, aggregate, head-mean.
// No workspace, no memset, no atomics, one dispatch (~6us overhead saved).

constexpr int kB = 32, kW = 128, kF = 64, kH = 2, kD = 128, kHD = 256;
constexpr float kNeg = 0.2f;

__device__ __forceinline__ float lrelu(float v) { return fmaxf(v, kNeg * v); }

// u[] union: xw[128][68] (x transposed, projection phase) then
// pbuf[4][2][8][132] (aggregate partials). 8704 words = 34 KB.
#define XW(w, n) u[(w) * 68 + (n)]
#define PBUF(jp, h, i, d) u[(((jp) * 2 + (h)) * 8 + (i)) * 132 + (d)]

__global__ __launch_bounds__(512) void gat_fused(
    const float* __restrict__ x, const float* __restrict__ Wl,
    const float* __restrict__ Wr, const float* __restrict__ attn_a,
    const float* __restrict__ bias, float* __restrict__ out) {
  __shared__ float el[kH][kF][kD + 4];  // 67.6 KB
  __shared__ float er[kH][8][kD + 4];   //  8.4 KB
  __shared__ float sAT[kH][kF][8];      //  4 KB  (alphas [h][j][i])
  __shared__ float u[8704];             // 34 KB  (xw / pbuf union)

  const int b = blockIdx.x >> 3;
  const int i0 = (blockIdx.x & 7) << 3;
  const int t = threadIdx.x;

  // ---- stage x[b] transposed: xw[w][n] = x[b][w][n] ----
  const float* xb = x + b * (kW * kF);
#pragma unroll
  for (int k = 0; k < 16; ++k) {
    const int idx = t + (k << 9);
    XW(idx >> 6, idx & 63) = xb[idx];
  }
  __syncthreads();

  // ---- projection el (all 64 j, both heads): thread (jq=t>>5, dg=t&31) ----
  {
    const int dg = t & 31;
    const int j0 = (t >> 5) << 2;
    const int c = dg << 2;               // head-0 col; head-1 = c+128
    float a0[4][4] = {};
    float a1[4][4] = {};
    const float* w0p = Wl + c;
    const float* w1p = Wl + kD + c;
#pragma unroll 4
    for (int w = 0; w < kW; ++w) {
      const float4 w0 = *(const float4*)&w0p[w * kHD];  // L1/L2-hot stream
      const float4 w1 = *(const float4*)&w1p[w * kHD];
      const float4 xv = *(const float4*)&XW(w, j0);     // 2-addr broadcast
      const float xa[4] = {xv.x, xv.y, xv.z, xv.w};
      const float wa0[4] = {w0.x, w0.y, w0.z, w0.w};
      const float wa1[4] = {w1.x, w1.y, w1.z, w1.w};
#pragma unroll
      for (int jj = 0; jj < 4; ++jj)
#pragma unroll
        for (int cc = 0; cc < 4; ++cc) {
          a0[jj][cc] = fmaf(xa[jj], wa0[cc], a0[jj][cc]);
          a1[jj][cc] = fmaf(xa[jj], wa1[cc], a1[jj][cc]);
        }
    }
#pragma unroll
    for (int jj = 0; jj < 4; ++jj) {
      *(float4*)&el[0][j0 + jj][c] =
          make_float4(a0[jj][0], a0[jj][1], a0[jj][2], a0[jj][3]);
      *(float4*)&el[1][j0 + jj][c] =
          make_float4(a1[jj][0], a1[jj][1], a1[jj][2], a1[jj][3]);
    }
  }

  // ---- projection er (8 dst rows, both heads): thread (i=t>>6, cg=t&63) ----
  {
    const int i = t >> 6;                 // = wave id -> xw read is broadcast
    const int c = (t & 63) << 2;          // 0..252 spans both heads
    const int n = i0 + i;
    float a[4] = {};
    const float* wrp = Wr + c;
#pragma unroll 4
    for (int w = 0; w < kW; ++w) {
      const float xs = XW(w, n);
      const float4 w4 = *(const float4*)&wrp[w * kHD];
      a[0] = fmaf(xs, w4.x, a[0]);
      a[1] = fmaf(xs, w4.y, a[1]);
      a[2] = fmaf(xs, w4.z, a[2]);
      a[3] = fmaf(xs, w4.w, a[3]);
    }
    *(float4*)&er[c >> 7][i][c & 127] = make_float4(a[0], a[1], a[2], a[3]);
  }
  __syncthreads();

  // ---- scores + in-wave softmax: thread = h(1b) | i(3b) | jl(5b) ----
  // 32 threads sharing (h,i) are an aligned 32-lane group.
  {
    const int jl = t & 31;
    const int i = (t >> 5) & 7;
    const int h = t >> 8;
    const int j1 = jl + 32;
    const float* avp = attn_a + h * kD;   // global, 1 addr/wave
    float e0 = 0.f, e1 = 0.f;
#pragma unroll
    for (int dv = 0; dv < kD; dv += 4) {
      const float4 a4 = *(const float4*)&avp[dv];
      const float4 rv = *(const float4*)&er[h][i][dv];
      const float4 p0 = *(const float4*)&el[h][jl][dv];
      const float4 p1 = *(const float4*)&el[h][j1][dv];
      e0 = fmaf(lrelu(p0.x + rv.x), a4.x, e0);
      e0 = fmaf(lrelu(p0.y + rv.y), a4.y, e0);
      e0 = fmaf(lrelu(p0.z + rv.z), a4.z, e0);
      e0 = fmaf(lrelu(p0.w + rv.w), a4.w, e0);
      e1 = fmaf(lrelu(p1.x + rv.x), a4.x, e1);
      e1 = fmaf(lrelu(p1.y + rv.y), a4.y, e1);
      e1 = fmaf(lrelu(p1.z + rv.z), a4.z, e1);
      e1 = fmaf(lrelu(p1.w + rv.w), a4.w, e1);
    }
    float m = fmaxf(e0, e1);
#pragma unroll
    for (int off = 1; off < 32; off <<= 1) m = fmaxf(m, __shfl_xor(m, off));
    const float x0 = __expf(e0 - m);
    const float x1 = __expf(e1 - m);
    float s = x0 + x1;
#pragma unroll
    for (int off = 1; off < 32; off <<= 1) s += __shfl_xor(s, off);
    const float inv = 1.f / s;
    sAT[h][jl][i] = x0 * inv;
    sAT[h][j1][i] = x1 * inv;
  }
  __syncthreads();

  // ---- aggregate: thread = jp(2b) | h(1b) | dg(5b) | ip(1b) ----
  // 4i x 4d register tile over a 16-j quarter; partials to pbuf (xw is dead).
  {
    const int ip = t & 1;
    const int dg = (t >> 1) & 31;
    const int h = (t >> 6) & 1;
    const int jp = t >> 7;
    const int d0 = dg << 2;
    const int ib = ip << 2;
    float acc[4][4] = {};
#pragma unroll
    for (int jj = 0; jj < 16; ++jj) {
      const int j = (jp << 4) + jj;
      const float4 al = *(const float4*)&sAT[h][j][ib];
      const float4 ev = *(const float4*)&el[h][j][d0];
      acc[0][0] = fmaf(al.x, ev.x, acc[0][0]);
      acc[0][1] = fmaf(al.x, ev.y, acc[0][1]);
      acc[0][2] = fmaf(al.x, ev.z, acc[0][2]);
      acc[0][3] = fmaf(al.x, ev.w, acc[0][3]);
      acc[1][0] = fmaf(al.y, ev.x, acc[1][0]);
      acc[1][1] = fmaf(al.y, ev.y, acc[1][1]);
      acc[1][2] = fmaf(al.y, ev.z, acc[1][2]);
      acc[1][3] = fmaf(al.y, ev.w, acc[1][3]);
      acc[2][0] = fmaf(al.z, ev.x, acc[2][0]);
      acc[2][1] = fmaf(al.z, ev.y, acc[2][1]);
      acc[2][2] = fmaf(al.z, ev.z, acc[2][2]);
      acc[2][3] = fmaf(al.z, ev.w, acc[2][3]);
      acc[3][0] = fmaf(al.w, ev.x, acc[3][0]);
      acc[3][1] = fmaf(al.w, ev.y, acc[3][1]);
      acc[3][2] = fmaf(al.w, ev.z, acc[3][2]);
      acc[3][3] = fmaf(al.w, ev.w, acc[3][3]);
    }
#pragma unroll
    for (int ii = 0; ii < 4; ++ii) {
      *(float4*)&PBUF(jp, h, ib + ii, d0) =
          make_float4(acc[ii][0], acc[ii][1], acc[ii][2], acc[ii][3]);
    }
  }
  __syncthreads();

  // ---- final: sum jp & heads, bias, mean, store. thread = d(7b)|ipr(2b) ----
  {
    const int ipr = t & 3;     // i-pair: i = 2*ipr, 2*ipr+1
    const int d = t >> 2;
    float s0 = 0.f, s1 = 0.f;
#pragma unroll
    for (int jp = 0; jp < 4; ++jp)
#pragma unroll
      for (int h = 0; h < 2; ++h) {
        const float* p = &PBUF(jp, h, ipr << 1, d);
        s0 += p[0];
        s1 += p[132];
      }
    const float bs = 0.5f * (bias[d] + bias[kD + d]);
    float2 v;
    v.x = 0.5f * s0 + bs;
    v.y = 0.5f * s1 + bs;
    *(float2*)&out[b * (kD * kF) + d * kF + i0 + (ipr << 1)] = v;
  }
}

extern "C" void kernel_launch(void* const* d_in, const int* in_sizes, int n_in,
                              void* d_out, int out_size, void* d_ws,
                              size_t ws_size, hipStream_t stream) {
  (void)in_sizes; (void)n_in; (void)d_ws; (void)ws_size; (void)out_size;
  const float* x = (const float*)d_in[0];
  const float* Wl = (const float*)d_in[1];
  const float* Wr = (const float*)d_in[2];
  const float* attn_a = (const float*)d_in[3];
  const float* bias = (const float*)d_in[4];
  float* out = (float*)d_out;

  gat_fused<<<dim3(kB * 8), dim3(512), 0, stream>>>(x, Wl, Wr, attn_a, bias,
                                                    out);
}

// Round 8
// 32.312 us; speedup vs baseline: 1.0166x; 1.0166x over previous
//
#include <hip/hip_runtime.h>
#include <hip/hip_bf16.h>

// GATv2 dense complete-graph, B=32, W=128 (in-feat), F=64 (nodes), H=2, D=128.
// Two kernels, 1024-thread blocks, grid 256 (1 block/CU, 16 waves/CU = 4/SIMD).
// K1: projection, x tile in LDS (broadcast b64 reads), W streamed from L1/L2.
// K2: scores with d-split across lane bit5 (+shfl combine), in-wave softmax,
//     register-tiled aggregate, head-mean, direct stores. No memset/atomics.

constexpr int kB = 32, kW = 128, kF = 64, kH = 2, kD = 128, kHD = 256;
constexpr float kNeg = 0.2f;

__device__ __forceinline__ float lrelu(float v) { return fmaxf(v, kNeg * v); }

// ---------------- K1: projection ----------------
// grid = B*8 (c-slices of 32), block = 1024. thread: 2 rows x 1 col x (l,r).
__global__ __launch_bounds__(1024) void gat_proj(
    const float* __restrict__ x, const float* __restrict__ Wl,
    const float* __restrict__ Wr, float* __restrict__ elw,
    float* __restrict__ erw) {
  __shared__ float xw[kW][kF + 4];  // 34 KB
  const int b = blockIdx.x >> 3;
  const int c0 = (blockIdx.x & 7) << 5;
  const int t = threadIdx.x;

  const float* xb = x + b * (kW * kF);
#pragma unroll
  for (int k = 0; k < 8; ++k) {
    const int idx = t + (k << 10);
    xw[idx >> 6][idx & 63] = xb[idx];  // xw[w][n] = x[b][w][n]
  }
  __syncthreads();

  const int c = c0 + (t & 31);
  const int n0 = (t >> 5) << 1;  // 2 rows per thread
  float l0 = 0.f, l1 = 0.f, r0 = 0.f, r1 = 0.f;
  const float* wlp = Wl + c;
  const float* wrp = Wr + c;

#pragma unroll 8
  for (int w = 0; w < kW; ++w) {
    const float wl = wlp[w * kHD];  // L1/L2-hot, coalesced 128B per wave
    const float wr = wrp[w * kHD];
    const float2 xa = *(const float2*)&xw[w][n0];  // 2-addr broadcast b64
    l0 = fmaf(xa.x, wl, l0);
    r0 = fmaf(xa.x, wr, r0);
    l1 = fmaf(xa.y, wl, l1);
    r1 = fmaf(xa.y, wr, r1);
  }

  const int base = (b * kF + n0) * kHD + c;
  elw[base] = l0;
  elw[base + kHD] = l1;
  erw[base] = r0;
  erw[base + kHD] = r1;
}

// ---------------- K2: attention (both heads per block) ----------------
// grid = B*8 (i-tiles of 8), block = 1024.
__global__ __launch_bounds__(1024) void gat_attn(
    const float* __restrict__ elw, const float* __restrict__ erw,
    const float* __restrict__ attn_a, const float* __restrict__ bias,
    float* __restrict__ out) {
  __shared__ float el[kH][kF][kD + 4];      // 67.6 KB
  __shared__ float sAT[kH][kF][8];          //  4 KB (alphas [h][j][i])
  __shared__ float pbuf[4][kH][8][kD + 4];  // 33.8 KB (j-quarter partials)

  const int b = blockIdx.x >> 3;
  const int i0 = (blockIdx.x & 7) << 3;
  const int t = threadIdx.x;

  // ---- stage el: 4096 float4 slots / 1024 threads = 4 each ----
  {
    const float* elb = elw + b * (kF * kHD);
#pragma unroll
    for (int k = 0; k < 4; ++k) {
      const int s = t + (k << 10);
      const int h = s >> 11;
      const int n = (s >> 5) & 63;
      const int dv = (s & 31) << 2;
      *(float4*)&el[h][n][dv] = *(const float4*)&elb[n * kHD + h * kD + dv];
    }
  }
  __syncthreads();

  // ---- scores + in-wave softmax ----
  // t = h(1b) | i(3b) | dh(1b) | jh(1b) | q(4b): wave = one (h,i) pair;
  // lane bit5 (dh) splits the d-range, combined by one shfl_xor(32).
  // er/av read from GLOBAL (2 addrs/wave -> L1 broadcast, off the DS pipe).
  {
    const int q = t & 15;
    const int jh = (t >> 4) & 1;
    const int dh = (t >> 5) & 1;
    const int i = (t >> 6) & 7;
    const int h = t >> 9;
    const int j0 = q + (jh << 5);  // {0..15} u {32..47}
    const int j1 = j0 + 16;        // {16..31} u {48..63}
    const float* erp = erw + (b * kF + i0 + i) * kHD + h * kD;
    const float* avp = attn_a + h * kD;
    const int dvb = dh << 6;  // 0 or 64
    float e0a = 0.f, e0b = 0.f, e1a = 0.f, e1b = 0.f;
#pragma unroll
    for (int k = 0; k < 16; ++k) {
      const int dv = dvb + (k << 2);
      const float4 a4 = *(const float4*)&avp[dv];
      const float4 rv = *(const float4*)&erp[dv];
      const float4 p0 = *(const float4*)&el[h][j0][dv];
      const float4 p1 = *(const float4*)&el[h][j1][dv];
      if (k & 1) {
        e0b = fmaf(lrelu(p0.x + rv.x), a4.x, e0b);
        e0b = fmaf(lrelu(p0.y + rv.y), a4.y, e0b);
        e0b = fmaf(lrelu(p0.z + rv.z), a4.z, e0b);
        e0b = fmaf(lrelu(p0.w + rv.w), a4.w, e0b);
        e1b = fmaf(lrelu(p1.x + rv.x), a4.x, e1b);
        e1b = fmaf(lrelu(p1.y + rv.y), a4.y, e1b);
        e1b = fmaf(lrelu(p1.z + rv.z), a4.z, e1b);
        e1b = fmaf(lrelu(p1.w + rv.w), a4.w, e1b);
      } else {
        e0a = fmaf(lrelu(p0.x + rv.x), a4.x, e0a);
        e0a = fmaf(lrelu(p0.y + rv.y), a4.y, e0a);
        e0a = fmaf(lrelu(p0.z + rv.z), a4.z, e0a);
        e0a = fmaf(lrelu(p0.w + rv.w), a4.w, e0a);
        e1a = fmaf(lrelu(p1.x + rv.x), a4.x, e1a);
        e1a = fmaf(lrelu(p1.y + rv.y), a4.y, e1a);
        e1a = fmaf(lrelu(p1.z + rv.z), a4.z, e1a);
        e1a = fmaf(lrelu(p1.w + rv.w), a4.w, e1a);
      }
    }
    float e0 = e0a + e0b;
    float e1 = e1a + e1b;
    e0 += __shfl_xor(e0, 32);  // combine d-halves
    e1 += __shfl_xor(e1, 32);
    // softmax over j (64 j's held as 2 per lane across bits 0..4)
    float m = fmaxf(e0, e1);
#pragma unroll
    for (int off = 1; off < 32; off <<= 1) m = fmaxf(m, __shfl_xor(m, off));
    const float x0 = __expf(e0 - m);
    const float x1 = __expf(e1 - m);
    float s = x0 + x1;
#pragma unroll
    for (int off = 1; off < 32; off <<= 1) s += __shfl_xor(s, off);
    const float inv = 1.f / s;
    sAT[h][j0][i] = x0 * inv;  // dh pair writes same value (benign)
    sAT[h][j1][i] = x1 * inv;
  }
  __syncthreads();

  // ---- aggregate: t = h(1b) | isel(2b) | jq(2b) | dq(5b) ----
  // 2i x 4d register tile over a 16-j quarter; partials to pbuf.
  {
    const int dq = t & 31;
    const int jq = (t >> 5) & 3;
    const int isel = (t >> 7) & 3;
    const int h = t >> 9;
    const int d0 = dq << 2;
    const int i2 = isel << 1;
    float acc[2][4] = {};
#pragma unroll
    for (int jj = 0; jj < 16; ++jj) {
      const int j = (jq << 4) + jj;
      const float2 al = *(const float2*)&sAT[h][j][i2];  // broadcast b64
      const float4 ev = *(const float4*)&el[h][j][d0];   // contiguous b128
      acc[0][0] = fmaf(al.x, ev.x, acc[0][0]);
      acc[0][1] = fmaf(al.x, ev.y, acc[0][1]);
      acc[0][2] = fmaf(al.x, ev.z, acc[0][2]);
      acc[0][3] = fmaf(al.x, ev.w, acc[0][3]);
      acc[1][0] = fmaf(al.y, ev.x, acc[1][0]);
      acc[1][1] = fmaf(al.y, ev.y, acc[1][1]);
      acc[1][2] = fmaf(al.y, ev.z, acc[1][2]);
      acc[1][3] = fmaf(al.y, ev.w, acc[1][3]);
    }
    *(float4*)&pbuf[jq][h][i2][d0] =
        make_float4(acc[0][0], acc[0][1], acc[0][2], acc[0][3]);
    *(float4*)&pbuf[jq][h][i2 + 1][d0] =
        make_float4(acc[1][0], acc[1][1], acc[1][2], acc[1][3]);
  }
  __syncthreads();

  // ---- final: t = d(7b) | i(3b): sum 8 partials, bias, mean, store ----
  {
    const int i = t & 7;
    const int d = t >> 3;
    float s = 0.f;
#pragma unroll
    for (int jq = 0; jq < 4; ++jq)
#pragma unroll
      for (int h = 0; h < 2; ++h) s += pbuf[jq][h][i][d];
    const float bs = 0.5f * (bias[d] + bias[kD + d]);
    out[b * (kD * kF) + d * kF + i0 + i] = 0.5f * s + bs;
  }
}

extern "C" void kernel_launch(void* const* d_in, const int* in_sizes, int n_in,
                              void* d_out, int out_size, void* d_ws,
                              size_t ws_size, hipStream_t stream) {
  (void)in_sizes; (void)n_in; (void)ws_size; (void)out_size;
  const float* x = (const float*)d_in[0];
  const float* Wl = (const float*)d_in[1];
  const float* Wr = (const float*)d_in[2];
  const float* attn_a = (const float*)d_in[3];
  const float* bias = (const float*)d_in[4];
  float* out = (float*)d_out;

  float* elw = (float*)d_ws;                  // [B][64][256]
  float* erw = elw + (size_t)kB * kF * kHD;   // [B][64][256]

  gat_proj<<<dim3(kB * 8), dim3(1024), 0, stream>>>(x, Wl, Wr, elw, erw);
  gat_attn<<<dim3(kB * 8), dim3(1024), 0, stream>>>(elw, erw, attn_a, bias,
                                                    out);
}